// Round 3
// baseline (1803.397 us; speedup 1.0000x reference)
//
#include <hip/hip_runtime.h>
#include <stdint.h>

#define NTOK 343
#define SCALE 0.17677669529663687f

typedef uint32_t u32a __attribute__((may_alias));
typedef __attribute__((ext_vector_type(8))) short short8;
typedef short8 bfrag __attribute__((may_alias));
typedef __attribute__((ext_vector_type(4))) float f32x4;

static __device__ __forceinline__ uint16_t f2bf(float f) {
    uint32_t u = __float_as_uint(f);
    u += 0x7fffu + ((u >> 16) & 1u);
    return (uint16_t)(u >> 16);
}

// K0: padded fp32 bias table bias_p[h][352][352]; pad = 0
__global__ __launch_bounds__(256) void bias_pre(const float* __restrict__ rpb,
                                                const int* __restrict__ rel,
                                                float* __restrict__ bias_p) {
    int e = blockIdx.x * 256 + threadIdx.x;
    const int total = 3 * 352 * 352;
    if (e >= total) return;
    int h = e / (352 * 352);
    int rm = e % (352 * 352);
    int i = rm / 352, j = rm % 352;
    float v = 0.f;
    if (i < NTOK && j < NTOK) v = rpb[rel[i * NTOK + j] * 3 + h];
    bias_p[e] = v;
}

// K1: qkv projection, fp32 compute, bf16 store (unchanged from R2)
__global__ __launch_bounds__(256) void qkv_kernel(
    const float* __restrict__ x, const float* __restrict__ qkv_w,
    const float* __restrict__ qkv_b,
    uint16_t* __restrict__ q_ws, uint16_t* __restrict__ k_ws, uint16_t* __restrict__ v_ws)
{
    __shared__ float x_t[64 * 96];
    __shared__ float w_t[96 * 98];
    const int b = blockIdx.x / 6;
    const int n0 = (blockIdx.x % 6) * 64;
    const int tid = threadIdx.x;

    for (int e = tid; e < 64 * 96; e += 256) {
        int n = n0 + (e / 96);
        x_t[e] = (n < NTOK) ? x[(size_t)(b * NTOK + n) * 96 + (e % 96)] : 0.f;
    }

    const int tc = tid & 15, tn = tid >> 4;
    const int cb = tc * 6, nb = tn * 4;

    for (int chunk = 0; chunk < 3; ++chunk) {
        __syncthreads();
        for (int e = tid; e < 96 * 96; e += 256) {
            int c = e / 96, k = e % 96;
            w_t[k * 98 + c] = qkv_w[(size_t)(chunk * 96 + c) * 96 + k];
        }
        __syncthreads();

        float acc[4][6];
        #pragma unroll
        for (int i = 0; i < 4; ++i)
            #pragma unroll
            for (int u = 0; u < 6; ++u) acc[i][u] = 0.f;

        #pragma unroll 4
        for (int k = 0; k < 96; ++k) {
            float xr[4], wr[6];
            #pragma unroll
            for (int i = 0; i < 4; ++i) xr[i] = x_t[(nb + i) * 96 + k];
            #pragma unroll
            for (int u = 0; u < 6; ++u) wr[u] = w_t[k * 98 + cb + u];
            #pragma unroll
            for (int i = 0; i < 4; ++i)
                #pragma unroll
                for (int u = 0; u < 6; ++u)
                    acc[i][u] = fmaf(xr[i], wr[u], acc[i][u]);
        }

        const float scl = (chunk == 0) ? SCALE : 1.f;
        uint16_t* dst = (chunk == 0) ? q_ws : ((chunk == 1) ? k_ws : v_ws);
        #pragma unroll
        for (int i = 0; i < 4; ++i) {
            int n = n0 + nb + i;
            if (n < NTOK) {
                #pragma unroll
                for (int u = 0; u < 6; u += 2) {
                    int c = cb + u;
                    int hh = c >> 5, dd = c & 31;
                    float v0 = (acc[i][u]     + qkv_b[chunk * 96 + c])     * scl;
                    float v1 = (acc[i][u + 1] + qkv_b[chunk * 96 + c + 1]) * scl;
                    uint32_t pk = (uint32_t)f2bf(v0) | ((uint32_t)f2bf(v1) << 16);
                    *(u32a*)&dst[(size_t)((b * 3 + hh) * NTOK + n) * 32 + dd] = pk;
                }
            }
        }
    }
}

// K2: MFMA attention. Block = (b,h), 256 threads = 4 waves.
// Wave handles 16-row i-tiles. QK^T: A=Q-frag, B=K-frag direct from global.
// S C-layout: row i_local = 4*quad+r, col j_local = lane&15.
// PV: P staged per-wave in LDS (A-frag), V^T staged per-block in LDS (B-frag).
__global__ __launch_bounds__(256, 3) void attn_kernel(
    const uint16_t* __restrict__ q_ws, const uint16_t* __restrict__ k_ws,
    const uint16_t* __restrict__ v_ws, const float* __restrict__ mask,
    const float* __restrict__ bias_p, float* __restrict__ out_attn)
{
    __shared__ uint16_t vT[32 * 360];       // [d][token], stride 360 (16B-aligned rows)
    __shared__ uint16_t stage[4][16 * 40];  // per-wave P tile [i_local][j 0..31], stride 40

    const int bh = blockIdx.x;
    const int b = bh / 3, h = bh - b * 3, w = b & 63;
    const int tid = threadIdx.x, lane = tid & 63, wv = tid >> 6;
    const int m = lane & 15, quad = lane >> 4;

    // stage V^T (bf16), zero the pad tokens 343..351
    const u32a* vsrc = (const u32a*)(v_ws + (size_t)bh * NTOK * 32);
    for (int e = tid; e < NTOK * 16; e += 256) {
        int tok = e >> 4, dp = e & 15;
        uint32_t vv = vsrc[e];
        vT[(2 * dp) * 360 + tok]     = (uint16_t)(vv & 0xffffu);
        vT[(2 * dp + 1) * 360 + tok] = (uint16_t)(vv >> 16);
    }
    for (int e = tid; e < 32 * 9; e += 256) {
        int d = e / 9, tok = 343 + (e % 9);
        vT[d * 360 + tok] = 0;
    }
    __syncthreads();

    const uint16_t* qbase = q_ws + (size_t)bh * NTOK * 32;
    const uint16_t* kbase = k_ws + (size_t)bh * NTOK * 32;
    const float* maskw = mask + (size_t)w * NTOK * NTOK;
    const float* biash = bias_p + (size_t)h * 352 * 352;
    uint16_t* stg = stage[wv];

    for (int ti = wv; ti < 22; ti += 4) {
        const int i0 = ti * 16;
        // A-frag Q: lane holds Q[i0+m][quad*8 .. +8]  (16B coalesced)
        bfrag qf = *(const bfrag*)(qbase + (size_t)(i0 + m) * 32 + quad * 8);

        f32x4 S[22];
        #pragma unroll
        for (int t = 0; t < 22; ++t) S[t] = (f32x4){0.f, 0.f, 0.f, 0.f};

        #pragma unroll 2
        for (int t = 0; t < 22; ++t) {
            bfrag kf = *(const bfrag*)(kbase + (size_t)(t * 16 + m) * 32 + quad * 8);
            S[t] = __builtin_amdgcn_mfma_f32_16x16x32_bf16(qf, kf, S[t], 0, 0, 0);
        }

        // bias + mask + validity masking; track row max
        float mx[4];
        #pragma unroll
        for (int r = 0; r < 4; ++r) mx[r] = -1e30f;
        #pragma unroll
        for (int r = 0; r < 4; ++r) {
            const int ir = i0 + 4 * quad + r;
            const bool rowok = (ir < NTOK);
            const float* mrow = maskw + (size_t)ir * NTOK + m;
            const float* brow = biash + (size_t)ir * 352 + m;
            #pragma unroll
            for (int t = 0; t < 22; ++t) {
                float mk = rowok ? mrow[t * 16] : 0.f;   // exec-masked load
                float bs = brow[t * 16];                 // padded table, always safe
                float sv = S[t][r] + mk + bs;
                bool ok = rowok && (t * 16 + m < NTOK);
                sv = ok ? sv : -1e30f;                   // kills any garbage/NaN
                S[t][r] = sv;
                mx[r] = fmaxf(mx[r], sv);
            }
        }

        // softmax over j: per-lane regs done; reduce across the 16 lanes of the quad
        float inv_[4], sum[4];
        #pragma unroll
        for (int r = 0; r < 4; ++r) {
            float v = mx[r];
            v = fmaxf(v, __shfl_xor(v, 1));
            v = fmaxf(v, __shfl_xor(v, 2));
            v = fmaxf(v, __shfl_xor(v, 4));
            v = fmaxf(v, __shfl_xor(v, 8));
            mx[r] = v;
            sum[r] = 0.f;
        }
        #pragma unroll
        for (int t = 0; t < 22; ++t) {
            #pragma unroll
            for (int r = 0; r < 4; ++r) {
                float e = __expf(S[t][r] - mx[r]);
                S[t][r] = e;
                sum[r] += e;
            }
        }
        #pragma unroll
        for (int r = 0; r < 4; ++r) {
            float v = sum[r];
            v += __shfl_xor(v, 1);
            v += __shfl_xor(v, 2);
            v += __shfl_xor(v, 4);
            v += __shfl_xor(v, 8);
            inv_[r] = 1.f / v;
        }

        // PV: per pair of j-tiles, round-trip P through LDS to A-frag layout
        f32x4 O0 = (f32x4){0.f, 0.f, 0.f, 0.f};
        f32x4 O1 = (f32x4){0.f, 0.f, 0.f, 0.f};
        #pragma unroll 1
        for (int tp = 0; tp < 11; ++tp) {
            #pragma unroll
            for (int tt = 0; tt < 2; ++tt) {
                const int t = 2 * tp + tt;
                #pragma unroll
                for (int r = 0; r < 4; ++r) {
                    uint32_t u = __float_as_uint(S[t][r]) + 0x8000u;  // cheap RTN
                    stg[(4 * quad + r) * 40 + tt * 16 + m] = (uint16_t)(u >> 16);
                }
            }
            // same-wave LDS RAW: fence compiler, drain lgkm (proven R2 pattern)
            __asm__ __volatile__("" ::: "memory");
            __builtin_amdgcn_s_waitcnt(0xC07F);   // lgkmcnt(0)
            __asm__ __volatile__("" ::: "memory");

            bfrag pf = *(const bfrag*)(stg + m * 40 + quad * 8);
            bfrag v0 = *(const bfrag*)(vT + (size_t)m * 360 + tp * 32 + quad * 8);
            bfrag v1 = *(const bfrag*)(vT + (size_t)(m + 16) * 360 + tp * 32 + quad * 8);
            O0 = __builtin_amdgcn_mfma_f32_16x16x32_bf16(pf, v0, O0, 0, 0, 0);
            O1 = __builtin_amdgcn_mfma_f32_16x16x32_bf16(pf, v1, O1, 0, 0, 0);
            __asm__ __volatile__("" ::: "memory");  // keep next-iter writes after these reads
        }

        // epilogue: O rows 4*quad+r, cols m / m+16; scale by 1/sum
        #pragma unroll
        for (int r = 0; r < 4; ++r) {
            const int ir = i0 + 4 * quad + r;
            if (ir < NTOK) {
                float* orow = out_attn + ((size_t)b * NTOK + ir) * 96 + h * 32;
                orow[m]      = O0[r] * inv_[r];
                orow[m + 16] = O1[r] * inv_[r];
            }
        }
    }
}

// K3: output projection, in-place on d_out (unchanged from R2)
__global__ __launch_bounds__(256) void proj_kernel(
    const float* __restrict__ proj_w, const float* __restrict__ proj_b,
    float* __restrict__ out)
{
    __shared__ float a_t[64 * 96];
    __shared__ float w_t[96 * 98];
    const int r0 = blockIdx.x * 64;
    const int tid = threadIdx.x;
    for (int e = tid; e < 64 * 96; e += 256) a_t[e] = out[(size_t)r0 * 96 + e];
    for (int e = tid; e < 96 * 96; e += 256) {
        int c = e / 96, k = e % 96;
        w_t[k * 98 + c] = proj_w[(size_t)c * 96 + k];
    }
    __syncthreads();

    const int tc = tid & 15, tn = tid >> 4;
    const int cb = tc * 6, nb = tn * 4;
    float acc[4][6];
    #pragma unroll
    for (int i = 0; i < 4; ++i)
        #pragma unroll
        for (int u = 0; u < 6; ++u) acc[i][u] = 0.f;

    #pragma unroll 4
    for (int k = 0; k < 96; ++k) {
        float xr[4], wr[6];
        #pragma unroll
        for (int i = 0; i < 4; ++i) xr[i] = a_t[(nb + i) * 96 + k];
        #pragma unroll
        for (int u = 0; u < 6; ++u) wr[u] = w_t[k * 98 + cb + u];
        #pragma unroll
        for (int i = 0; i < 4; ++i)
            #pragma unroll
            for (int u = 0; u < 6; ++u)
                acc[i][u] = fmaf(xr[i], wr[u], acc[i][u]);
    }

    #pragma unroll
    for (int i = 0; i < 4; ++i) {
        int r = r0 + nb + i;
        #pragma unroll
        for (int u = 0; u < 6; ++u)
            out[(size_t)r * 96 + cb + u] = acc[i][u] + proj_b[cb + u];
    }
}

extern "C" void kernel_launch(void* const* d_in, const int* in_sizes, int n_in,
                              void* d_out, int out_size, void* d_ws, size_t ws_size,
                              hipStream_t stream) {
    const float* x      = (const float*)d_in[0];
    const float* mask   = (const float*)d_in[1];
    const float* qkv_w  = (const float*)d_in[2];
    const float* qkv_b  = (const float*)d_in[3];
    const float* proj_w = (const float*)d_in[4];
    const float* proj_b = (const float*)d_in[5];
    const float* rpb    = (const float*)d_in[6];
    const int*   rel    = (const int*)d_in[7];
    float* out = (float*)d_out;

    // ws layout: q,k,v bf16 [512*3][343][32] (33.7 MB each), then padded bias table
    uint16_t* q_ws = (uint16_t*)d_ws;
    uint16_t* k_ws = q_ws + 16859136;
    uint16_t* v_ws = k_ws + 16859136;
    float* bias_p = (float*)((char*)d_ws + 101154816);   // 3*352*352 fp32 = 1.49 MB

    bias_pre<<<dim3((3 * 352 * 352 + 255) / 256), 256, 0, stream>>>(rpb, rel, bias_p);
    qkv_kernel<<<dim3(512 * 6), 256, 0, stream>>>(x, qkv_w, qkv_b, q_ws, k_ws, v_ws);
    attn_kernel<<<dim3(512 * 3), 256, 0, stream>>>(q_ws, k_ws, v_ws, mask, bias_p, out);
    proj_kernel<<<dim3(2744), 256, 0, stream>>>(proj_w, proj_b, out);
}

// Round 4
// 971.382 us; speedup vs baseline: 1.8565x; 1.8565x over previous
//
#include <hip/hip_runtime.h>
#include <stdint.h>

#define NTOK 343
#define SCALE 0.17677669529663687f

typedef uint32_t u32a __attribute__((may_alias));
typedef __attribute__((ext_vector_type(8))) short short8;
typedef short8 bfrag __attribute__((may_alias));
typedef __attribute__((ext_vector_type(4))) float f32x4;

static __device__ __forceinline__ uint16_t f2bf(float f) {
    uint32_t u = __float_as_uint(f);
    u += 0x7fffu + ((u >> 16) & 1u);
    return (uint16_t)(u >> 16);
}

// K0: padded fp32 bias table bias_p[h][352][352]; pad = 0
__global__ __launch_bounds__(256) void bias_pre(const float* __restrict__ rpb,
                                                const int* __restrict__ rel,
                                                float* __restrict__ bias_p) {
    int e = blockIdx.x * 256 + threadIdx.x;
    const int total = 3 * 352 * 352;
    if (e >= total) return;
    int h = e / (352 * 352);
    int rm = e % (352 * 352);
    int i = rm / 352, j = rm % 352;
    float v = 0.f;
    if (i < NTOK && j < NTOK) v = rpb[rel[i * NTOK + j] * 3 + h];
    bias_p[e] = v;
}

// K1: qkv projection, fp32 compute, bf16 store (unchanged)
__global__ __launch_bounds__(256) void qkv_kernel(
    const float* __restrict__ x, const float* __restrict__ qkv_w,
    const float* __restrict__ qkv_b,
    uint16_t* __restrict__ q_ws, uint16_t* __restrict__ k_ws, uint16_t* __restrict__ v_ws)
{
    __shared__ float x_t[64 * 96];
    __shared__ float w_t[96 * 98];
    const int b = blockIdx.x / 6;
    const int n0 = (blockIdx.x % 6) * 64;
    const int tid = threadIdx.x;

    for (int e = tid; e < 64 * 96; e += 256) {
        int n = n0 + (e / 96);
        x_t[e] = (n < NTOK) ? x[(size_t)(b * NTOK + n) * 96 + (e % 96)] : 0.f;
    }

    const int tc = tid & 15, tn = tid >> 4;
    const int cb = tc * 6, nb = tn * 4;

    for (int chunk = 0; chunk < 3; ++chunk) {
        __syncthreads();
        for (int e = tid; e < 96 * 96; e += 256) {
            int c = e / 96, k = e % 96;
            w_t[k * 98 + c] = qkv_w[(size_t)(chunk * 96 + c) * 96 + k];
        }
        __syncthreads();

        float acc[4][6];
        #pragma unroll
        for (int i = 0; i < 4; ++i)
            #pragma unroll
            for (int u = 0; u < 6; ++u) acc[i][u] = 0.f;

        #pragma unroll 4
        for (int k = 0; k < 96; ++k) {
            float xr[4], wr[6];
            #pragma unroll
            for (int i = 0; i < 4; ++i) xr[i] = x_t[(nb + i) * 96 + k];
            #pragma unroll
            for (int u = 0; u < 6; ++u) wr[u] = w_t[k * 98 + cb + u];
            #pragma unroll
            for (int i = 0; i < 4; ++i)
                #pragma unroll
                for (int u = 0; u < 6; ++u)
                    acc[i][u] = fmaf(xr[i], wr[u], acc[i][u]);
        }

        const float scl = (chunk == 0) ? SCALE : 1.f;
        uint16_t* dst = (chunk == 0) ? q_ws : ((chunk == 1) ? k_ws : v_ws);
        #pragma unroll
        for (int i = 0; i < 4; ++i) {
            int n = n0 + nb + i;
            if (n < NTOK) {
                #pragma unroll
                for (int u = 0; u < 6; u += 2) {
                    int c = cb + u;
                    int hh = c >> 5, dd = c & 31;
                    float v0 = (acc[i][u]     + qkv_b[chunk * 96 + c])     * scl;
                    float v1 = (acc[i][u + 1] + qkv_b[chunk * 96 + c + 1]) * scl;
                    uint32_t pk = (uint32_t)f2bf(v0) | ((uint32_t)f2bf(v1) << 16);
                    *(u32a*)&dst[(size_t)((b * 3 + hh) * NTOK + n) * 32 + dd] = pk;
                }
            }
        }
    }
}

// K2: MFMA attention. Block = (b,h), 256 threads = 4 waves.
// ALL loops touching S[] are FULLY unrolled — partial unroll demotes S to
// scratch (R3: 6 GB of scratch HBM traffic, 68 VGPRs, 1352 us).
__global__ __launch_bounds__(256, 3) void attn_kernel(
    const uint16_t* __restrict__ q_ws, const uint16_t* __restrict__ k_ws,
    const uint16_t* __restrict__ v_ws, const float* __restrict__ mask,
    const float* __restrict__ bias_p, float* __restrict__ out_attn)
{
    __shared__ uint16_t vT[32 * 360];       // [d][token], stride 360
    __shared__ uint16_t stage[4][16 * 40];  // per-wave P tile, stride 40

    const int bh = blockIdx.x;
    const int b = bh / 3, h = bh - b * 3, w = b & 63;
    const int tid = threadIdx.x, lane = tid & 63, wv = tid >> 6;
    const int m = lane & 15, quad = lane >> 4;

    // stage V^T (bf16), zero the pad tokens 343..351
    const u32a* vsrc = (const u32a*)(v_ws + (size_t)bh * NTOK * 32);
    for (int e = tid; e < NTOK * 16; e += 256) {
        int tok = e >> 4, dp = e & 15;
        uint32_t vv = vsrc[e];
        vT[(2 * dp) * 360 + tok]     = (uint16_t)(vv & 0xffffu);
        vT[(2 * dp + 1) * 360 + tok] = (uint16_t)(vv >> 16);
    }
    for (int e = tid; e < 32 * 9; e += 256) {
        int d = e / 9, tok = 343 + (e % 9);
        vT[d * 360 + tok] = 0;
    }
    __syncthreads();

    const uint16_t* qbase = q_ws + (size_t)bh * NTOK * 32;
    const uint16_t* kbase = k_ws + (size_t)bh * NTOK * 32;
    const float* maskw = mask + (size_t)w * NTOK * NTOK;
    const float* biash = bias_p + (size_t)h * 352 * 352;
    uint16_t* stg = stage[wv];

    for (int ti = wv; ti < 22; ti += 4) {
        const int i0 = ti * 16;
        bfrag qf = *(const bfrag*)(qbase + (size_t)(i0 + m) * 32 + quad * 8);

        f32x4 S[22];
        #pragma unroll
        for (int t = 0; t < 22; ++t) S[t] = (f32x4){0.f, 0.f, 0.f, 0.f};

        #pragma unroll
        for (int t = 0; t < 22; ++t) {
            bfrag kf = *(const bfrag*)(kbase + (size_t)(t * 16 + m) * 32 + quad * 8);
            S[t] = __builtin_amdgcn_mfma_f32_16x16x32_bf16(qf, kf, S[t], 0, 0, 0);
        }

        // bias + mask + validity masking; track row max
        float mx[4];
        #pragma unroll
        for (int r = 0; r < 4; ++r) mx[r] = -1e30f;
        #pragma unroll
        for (int r = 0; r < 4; ++r) {
            const int ir = i0 + 4 * quad + r;
            const bool rowok = (ir < NTOK);
            const float* mrow = maskw + (size_t)ir * NTOK + m;
            const float* brow = biash + (size_t)ir * 352 + m;
            #pragma unroll
            for (int t = 0; t < 22; ++t) {
                float mk = rowok ? mrow[t * 16] : 0.f;   // exec-masked load
                float bs = brow[t * 16];                 // padded table, always safe
                float sv = S[t][r] + mk + bs;
                bool ok = rowok && (t * 16 + m < NTOK);
                sv = ok ? sv : -1e30f;
                S[t][r] = sv;
                mx[r] = fmaxf(mx[r], sv);
            }
        }

        // softmax over j: reduce across the 16 lanes of the quad
        float inv_[4], sum[4];
        #pragma unroll
        for (int r = 0; r < 4; ++r) {
            float v = mx[r];
            v = fmaxf(v, __shfl_xor(v, 1));
            v = fmaxf(v, __shfl_xor(v, 2));
            v = fmaxf(v, __shfl_xor(v, 4));
            v = fmaxf(v, __shfl_xor(v, 8));
            mx[r] = v;
            sum[r] = 0.f;
        }
        #pragma unroll
        for (int t = 0; t < 22; ++t) {
            #pragma unroll
            for (int r = 0; r < 4; ++r) {
                float e = __expf(S[t][r] - mx[r]);
                S[t][r] = e;
                sum[r] += e;
            }
        }
        #pragma unroll
        for (int r = 0; r < 4; ++r) {
            float v = sum[r];
            v += __shfl_xor(v, 1);
            v += __shfl_xor(v, 2);
            v += __shfl_xor(v, 4);
            v += __shfl_xor(v, 8);
            inv_[r] = 1.f / v;
        }

        // PV: per pair of j-tiles, round-trip P through LDS to A-frag layout.
        // FULLY unrolled (S indices must be compile-time constants).
        f32x4 O0 = (f32x4){0.f, 0.f, 0.f, 0.f};
        f32x4 O1 = (f32x4){0.f, 0.f, 0.f, 0.f};
        #pragma unroll
        for (int tp = 0; tp < 11; ++tp) {
            #pragma unroll
            for (int tt = 0; tt < 2; ++tt) {
                const int t = 2 * tp + tt;
                #pragma unroll
                for (int r = 0; r < 4; ++r) {
                    uint32_t u = __float_as_uint(S[t][r]) + 0x8000u;  // cheap RTN
                    stg[(4 * quad + r) * 40 + tt * 16 + m] = (uint16_t)(u >> 16);
                }
            }
            // same-wave LDS RAW: fence compiler, drain lgkm
            __asm__ __volatile__("" ::: "memory");
            __builtin_amdgcn_s_waitcnt(0xC07F);   // lgkmcnt(0)
            __asm__ __volatile__("" ::: "memory");

            bfrag pf = *(const bfrag*)(stg + m * 40 + quad * 8);
            bfrag v0 = *(const bfrag*)(vT + (size_t)m * 360 + tp * 32 + quad * 8);
            bfrag v1 = *(const bfrag*)(vT + (size_t)(m + 16) * 360 + tp * 32 + quad * 8);
            O0 = __builtin_amdgcn_mfma_f32_16x16x32_bf16(pf, v0, O0, 0, 0, 0);
            O1 = __builtin_amdgcn_mfma_f32_16x16x32_bf16(pf, v1, O1, 0, 0, 0);
            __asm__ __volatile__("" ::: "memory");  // keep next-iter writes after these reads
        }

        // epilogue
        #pragma unroll
        for (int r = 0; r < 4; ++r) {
            const int ir = i0 + 4 * quad + r;
            if (ir < NTOK) {
                float* orow = out_attn + ((size_t)b * NTOK + ir) * 96 + h * 32;
                orow[m]      = O0[r] * inv_[r];
                orow[m + 16] = O1[r] * inv_[r];
            }
        }
    }
}

// K3: output projection, in-place on d_out (unchanged)
__global__ __launch_bounds__(256) void proj_kernel(
    const float* __restrict__ proj_w, const float* __restrict__ proj_b,
    float* __restrict__ out)
{
    __shared__ float a_t[64 * 96];
    __shared__ float w_t[96 * 98];
    const int r0 = blockIdx.x * 64;
    const int tid = threadIdx.x;
    for (int e = tid; e < 64 * 96; e += 256) a_t[e] = out[(size_t)r0 * 96 + e];
    for (int e = tid; e < 96 * 96; e += 256) {
        int c = e / 96, k = e % 96;
        w_t[k * 98 + c] = proj_w[(size_t)c * 96 + k];
    }
    __syncthreads();

    const int tc = tid & 15, tn = tid >> 4;
    const int cb = tc * 6, nb = tn * 4;
    float acc[4][6];
    #pragma unroll
    for (int i = 0; i < 4; ++i)
        #pragma unroll
        for (int u = 0; u < 6; ++u) acc[i][u] = 0.f;

    #pragma unroll 4
    for (int k = 0; k < 96; ++k) {
        float xr[4], wr[6];
        #pragma unroll
        for (int i = 0; i < 4; ++i) xr[i] = a_t[(nb + i) * 96 + k];
        #pragma unroll
        for (int u = 0; u < 6; ++u) wr[u] = w_t[k * 98 + cb + u];
        #pragma unroll
        for (int i = 0; i < 4; ++i)
            #pragma unroll
            for (int u = 0; u < 6; ++u)
                acc[i][u] = fmaf(xr[i], wr[u], acc[i][u]);
    }

    #pragma unroll
    for (int i = 0; i < 4; ++i) {
        int r = r0 + nb + i;
        #pragma unroll
        for (int u = 0; u < 6; ++u)
            out[(size_t)r * 96 + cb + u] = acc[i][u] + proj_b[cb + u];
    }
}

extern "C" void kernel_launch(void* const* d_in, const int* in_sizes, int n_in,
                              void* d_out, int out_size, void* d_ws, size_t ws_size,
                              hipStream_t stream) {
    const float* x      = (const float*)d_in[0];
    const float* mask   = (const float*)d_in[1];
    const float* qkv_w  = (const float*)d_in[2];
    const float* qkv_b  = (const float*)d_in[3];
    const float* proj_w = (const float*)d_in[4];
    const float* proj_b = (const float*)d_in[5];
    const float* rpb    = (const float*)d_in[6];
    const int*   rel    = (const int*)d_in[7];
    float* out = (float*)d_out;

    uint16_t* q_ws = (uint16_t*)d_ws;
    uint16_t* k_ws = q_ws + 16859136;
    uint16_t* v_ws = k_ws + 16859136;
    float* bias_p = (float*)((char*)d_ws + 101154816);   // 3*352*352 fp32

    bias_pre<<<dim3((3 * 352 * 352 + 255) / 256), 256, 0, stream>>>(rpb, rel, bias_p);
    qkv_kernel<<<dim3(512 * 6), 256, 0, stream>>>(x, qkv_w, qkv_b, q_ws, k_ws, v_ws);
    attn_kernel<<<dim3(512 * 3), 256, 0, stream>>>(q_ws, k_ws, v_ws, mask, bias_p, out);
    proj_kernel<<<dim3(2744), 256, 0, stream>>>(proj_w, proj_b, out);
}

// Round 5
// 783.415 us; speedup vs baseline: 2.3020x; 1.2399x over previous
//
#include <hip/hip_runtime.h>
#include <stdint.h>

#define NTOK 343
#define SCALE 0.17677669529663687f

typedef uint32_t u32a __attribute__((may_alias));
typedef __attribute__((ext_vector_type(8))) short short8;
typedef short8 bfrag __attribute__((may_alias));
typedef __attribute__((ext_vector_type(4))) float f32x4;

static __device__ __forceinline__ uint16_t f2bf(float f) {
    uint32_t u = __float_as_uint(f);
    u += 0x7fffu + ((u >> 16) & 1u);
    return (uint16_t)(u >> 16);
}
static __device__ __forceinline__ float bflo(uint32_t p) { return __uint_as_float(p << 16); }
static __device__ __forceinline__ float bfhi(uint32_t p) { return __uint_as_float(p & 0xffff0000u); }

// K0: packed bf16 combined (mask+bias) table.
// comb[w][h][i][tp*16+m] = pack(bf16(C[i][tp*32+m]), bf16(C[i][tp*32+16+m]))
// where C[i][j] = mask[w][i][j] + rpb[rel[i][j]][h].
__global__ __launch_bounds__(256) void comb_pre(const float* __restrict__ mask,
                                                const float* __restrict__ rpb,
                                                const int* __restrict__ rel,
                                                u32a* __restrict__ comb) {
    int e = blockIdx.x * 256 + threadIdx.x;
    const int total = 64 * 3 * NTOK * 176;
    if (e >= total) return;
    int m16 = e & 15;
    int tp = (e >> 4) % 11;
    int rest = e / 176;
    int i = rest % NTOK;
    int wh = rest / NTOK;
    int h = wh % 3, w = wh / 3;
    int j0 = tp * 32 + m16;
    int j1 = j0 + 16;
    const float* mrow = mask + ((size_t)w * NTOK + i) * NTOK;
    const int* rrow = rel + i * NTOK;
    float c0 = mrow[j0] + rpb[rrow[j0] * 3 + h];
    float c1 = (j1 < NTOK) ? (mrow[j1] + rpb[rrow[j1] * 3 + h]) : 0.f;
    comb[e] = (uint32_t)f2bf(c0) | ((uint32_t)f2bf(c1) << 16);
}

// K1: qkv projection, fp32 compute, bf16 store (unchanged)
__global__ __launch_bounds__(256) void qkv_kernel(
    const float* __restrict__ x, const float* __restrict__ qkv_w,
    const float* __restrict__ qkv_b,
    uint16_t* __restrict__ q_ws, uint16_t* __restrict__ k_ws, uint16_t* __restrict__ v_ws)
{
    __shared__ float x_t[64 * 96];
    __shared__ float w_t[96 * 98];
    const int b = blockIdx.x / 6;
    const int n0 = (blockIdx.x % 6) * 64;
    const int tid = threadIdx.x;

    for (int e = tid; e < 64 * 96; e += 256) {
        int n = n0 + (e / 96);
        x_t[e] = (n < NTOK) ? x[(size_t)(b * NTOK + n) * 96 + (e % 96)] : 0.f;
    }

    const int tc = tid & 15, tn = tid >> 4;
    const int cb = tc * 6, nb = tn * 4;

    for (int chunk = 0; chunk < 3; ++chunk) {
        __syncthreads();
        for (int e = tid; e < 96 * 96; e += 256) {
            int c = e / 96, k = e % 96;
            w_t[k * 98 + c] = qkv_w[(size_t)(chunk * 96 + c) * 96 + k];
        }
        __syncthreads();

        float acc[4][6];
        #pragma unroll
        for (int i = 0; i < 4; ++i)
            #pragma unroll
            for (int u = 0; u < 6; ++u) acc[i][u] = 0.f;

        #pragma unroll 4
        for (int k = 0; k < 96; ++k) {
            float xr[4], wr[6];
            #pragma unroll
            for (int i = 0; i < 4; ++i) xr[i] = x_t[(nb + i) * 96 + k];
            #pragma unroll
            for (int u = 0; u < 6; ++u) wr[u] = w_t[k * 98 + cb + u];
            #pragma unroll
            for (int i = 0; i < 4; ++i)
                #pragma unroll
                for (int u = 0; u < 6; ++u)
                    acc[i][u] = fmaf(xr[i], wr[u], acc[i][u]);
        }

        const float scl = (chunk == 0) ? SCALE : 1.f;
        uint16_t* dst = (chunk == 0) ? q_ws : ((chunk == 1) ? k_ws : v_ws);
        #pragma unroll
        for (int i = 0; i < 4; ++i) {
            int n = n0 + nb + i;
            if (n < NTOK) {
                #pragma unroll
                for (int u = 0; u < 6; u += 2) {
                    int c = cb + u;
                    int hh = c >> 5, dd = c & 31;
                    float v0 = (acc[i][u]     + qkv_b[chunk * 96 + c])     * scl;
                    float v1 = (acc[i][u + 1] + qkv_b[chunk * 96 + c + 1]) * scl;
                    uint32_t pk = (uint32_t)f2bf(v0) | ((uint32_t)f2bf(v1) << 16);
                    *(u32a*)&dst[(size_t)((b * 3 + hh) * NTOK + n) * 32 + dd] = pk;
                }
            }
        }
    }
}

// K2: MFMA attention. Block = (b,h), 256 threads = 4 waves.
// All S[]-indexing loops fully unrolled (partial unroll -> scratch, R3).
// Packed bf16 comb table: 44 loads / i-tile. PV staged in 2 halves (1 lgkm
// drain each) instead of 11 per-pair drains.
__global__ __launch_bounds__(256, 3) void attn_kernel(
    const uint16_t* __restrict__ q_ws, const uint16_t* __restrict__ k_ws,
    const uint16_t* __restrict__ v_ws, const u32a* __restrict__ comb,
    float* __restrict__ out_attn)
{
    __shared__ uint16_t vT[32 * 360];        // [d][token], stride 360
    __shared__ uint16_t pstage[4][16 * 200]; // per-wave P, 12 tiles max, stride 200

    const int bh = blockIdx.x;
    const int b = bh / 3, h = bh - b * 3, w = b & 63;
    const int tid = threadIdx.x, lane = tid & 63, wv = tid >> 6;
    const int m = lane & 15, quad = lane >> 4;

    // stage V^T (bf16), zero the pad tokens 343..351
    const u32a* vsrc = (const u32a*)(v_ws + (size_t)bh * NTOK * 32);
    for (int e = tid; e < NTOK * 16; e += 256) {
        int tok = e >> 4, dp = e & 15;
        uint32_t vv = vsrc[e];
        vT[(2 * dp) * 360 + tok]     = (uint16_t)(vv & 0xffffu);
        vT[(2 * dp + 1) * 360 + tok] = (uint16_t)(vv >> 16);
    }
    for (int e = tid; e < 32 * 9; e += 256) {
        int d = e / 9, tok = 343 + (e % 9);
        vT[d * 360 + tok] = 0;
    }
    __syncthreads();

    const uint16_t* qbase = q_ws + (size_t)bh * NTOK * 32;
    const uint16_t* kbase = k_ws + (size_t)bh * NTOK * 32;
    const int wh = w * 3 + h;
    uint16_t* stg = pstage[wv];

    for (int ti = wv; ti < 22; ti += 4) {
        const int i0 = ti * 16;
        bfrag qf = *(const bfrag*)(qbase + (size_t)(i0 + m) * 32 + quad * 8);

        f32x4 S[22];
        #pragma unroll
        for (int t = 0; t < 22; ++t) S[t] = (f32x4){0.f, 0.f, 0.f, 0.f};

        #pragma unroll
        for (int t = 0; t < 22; ++t) {
            bfrag kf = *(const bfrag*)(kbase + (size_t)(t * 16 + m) * 32 + quad * 8);
            S[t] = __builtin_amdgcn_mfma_f32_16x16x32_bf16(qf, kf, S[t], 0, 0, 0);
        }

        // combined bias+mask (packed bf16 pairs) + validity; track row max
        float mx[4];
        #pragma unroll
        for (int r = 0; r < 4; ++r) mx[r] = -1e30f;
        #pragma unroll
        for (int r = 0; r < 4; ++r) {
            const int ir = i0 + 4 * quad + r;
            const bool rowok = (ir < NTOK);
            const u32a* crow = comb + ((size_t)(wh * NTOK + ir)) * 176 + m;
            #pragma unroll
            for (int tp = 0; tp < 11; ++tp) {
                uint32_t cw = rowok ? crow[tp * 16] : 0u;   // exec-masked load
                float sv0 = S[2 * tp][r] + bflo(cw);        // j0 = tp*32+m < 343 always
                float sv1 = S[2 * tp + 1][r] + bfhi(cw);
                bool ok1 = rowok && (tp * 32 + 16 + m < NTOK);
                sv0 = rowok ? sv0 : -1e30f;
                sv1 = ok1 ? sv1 : -1e30f;
                S[2 * tp][r] = sv0;
                S[2 * tp + 1][r] = sv1;
                mx[r] = fmaxf(mx[r], fmaxf(sv0, sv1));
            }
        }

        // softmax over j: reduce across the 16 lanes of the quad
        float inv_[4], sum[4];
        #pragma unroll
        for (int r = 0; r < 4; ++r) {
            float v = mx[r];
            v = fmaxf(v, __shfl_xor(v, 1));
            v = fmaxf(v, __shfl_xor(v, 2));
            v = fmaxf(v, __shfl_xor(v, 4));
            v = fmaxf(v, __shfl_xor(v, 8));
            mx[r] = v;
            sum[r] = 0.f;
        }
        #pragma unroll
        for (int t = 0; t < 22; ++t) {
            #pragma unroll
            for (int r = 0; r < 4; ++r) {
                float e = __expf(S[t][r] - mx[r]);
                S[t][r] = e;
                sum[r] += e;
            }
        }
        #pragma unroll
        for (int r = 0; r < 4; ++r) {
            float v = sum[r];
            v += __shfl_xor(v, 1);
            v += __shfl_xor(v, 2);
            v += __shfl_xor(v, 4);
            v += __shfl_xor(v, 8);
            inv_[r] = 1.f / v;
        }

        // PV in 2 halves: half0 = tiles 0..11 (6 k-chunks), half1 = 12..21 (5).
        f32x4 O0 = (f32x4){0.f, 0.f, 0.f, 0.f};
        f32x4 O1 = (f32x4){0.f, 0.f, 0.f, 0.f};
        #pragma unroll
        for (int hf = 0; hf < 2; ++hf) {
            const int tbase = hf ? 12 : 0;
            const int nt = hf ? 10 : 12;
            const int nch = hf ? 5 : 6;
            #pragma unroll
            for (int tt = 0; tt < 12; ++tt) {
                if (tt < nt) {
                    const int t = tbase + tt;
                    #pragma unroll
                    for (int r = 0; r < 4; ++r) {
                        uint32_t u = __float_as_uint(S[t][r]) + 0x8000u;  // cheap RTN
                        stg[(4 * quad + r) * 200 + tt * 16 + m] = (uint16_t)(u >> 16);
                    }
                }
            }
            // one drain per half; same-wave DS is in-order
            __asm__ __volatile__("" ::: "memory");
            __builtin_amdgcn_s_waitcnt(0xC07F);   // lgkmcnt(0)
            __asm__ __volatile__("" ::: "memory");

            #pragma unroll
            for (int c = 0; c < 6; ++c) {
                if (c < nch) {
                    const int jj = hf * 192 + c * 32;
                    bfrag pf = *(const bfrag*)(stg + m * 200 + c * 32 + quad * 8);
                    bfrag v0 = *(const bfrag*)(vT + (size_t)m * 360 + jj + quad * 8);
                    bfrag v1 = *(const bfrag*)(vT + (size_t)(m + 16) * 360 + jj + quad * 8);
                    O0 = __builtin_amdgcn_mfma_f32_16x16x32_bf16(pf, v0, O0, 0, 0, 0);
                    O1 = __builtin_amdgcn_mfma_f32_16x16x32_bf16(pf, v1, O1, 0, 0, 0);
                }
            }
            __asm__ __volatile__("" ::: "memory");  // half1 writes stay after half0 reads
        }

        // epilogue
        #pragma unroll
        for (int r = 0; r < 4; ++r) {
            const int ir = i0 + 4 * quad + r;
            if (ir < NTOK) {
                float* orow = out_attn + ((size_t)b * NTOK + ir) * 96 + h * 32;
                orow[m]      = O0[r] * inv_[r];
                orow[m + 16] = O1[r] * inv_[r];
            }
        }
    }
}

// K3: output projection, in-place on d_out (unchanged)
__global__ __launch_bounds__(256) void proj_kernel(
    const float* __restrict__ proj_w, const float* __restrict__ proj_b,
    float* __restrict__ out)
{
    __shared__ float a_t[64 * 96];
    __shared__ float w_t[96 * 98];
    const int r0 = blockIdx.x * 64;
    const int tid = threadIdx.x;
    for (int e = tid; e < 64 * 96; e += 256) a_t[e] = out[(size_t)r0 * 96 + e];
    for (int e = tid; e < 96 * 96; e += 256) {
        int c = e / 96, k = e % 96;
        w_t[k * 98 + c] = proj_w[(size_t)c * 96 + k];
    }
    __syncthreads();

    const int tc = tid & 15, tn = tid >> 4;
    const int cb = tc * 6, nb = tn * 4;
    float acc[4][6];
    #pragma unroll
    for (int i = 0; i < 4; ++i)
        #pragma unroll
        for (int u = 0; u < 6; ++u) acc[i][u] = 0.f;

    #pragma unroll 4
    for (int k = 0; k < 96; ++k) {
        float xr[4], wr[6];
        #pragma unroll
        for (int i = 0; i < 4; ++i) xr[i] = a_t[(nb + i) * 96 + k];
        #pragma unroll
        for (int u = 0; u < 6; ++u) wr[u] = w_t[k * 98 + cb + u];
        #pragma unroll
        for (int i = 0; i < 4; ++i)
            #pragma unroll
            for (int u = 0; u < 6; ++u)
                acc[i][u] = fmaf(xr[i], wr[u], acc[i][u]);
    }

    #pragma unroll
    for (int i = 0; i < 4; ++i) {
        int r = r0 + nb + i;
        #pragma unroll
        for (int u = 0; u < 6; ++u)
            out[(size_t)r * 96 + cb + u] = acc[i][u] + proj_b[cb + u];
    }
}

extern "C" void kernel_launch(void* const* d_in, const int* in_sizes, int n_in,
                              void* d_out, int out_size, void* d_ws, size_t ws_size,
                              hipStream_t stream) {
    const float* x      = (const float*)d_in[0];
    const float* mask   = (const float*)d_in[1];
    const float* qkv_w  = (const float*)d_in[2];
    const float* qkv_b  = (const float*)d_in[3];
    const float* proj_w = (const float*)d_in[4];
    const float* proj_b = (const float*)d_in[5];
    const float* rpb    = (const float*)d_in[6];
    const int*   rel    = (const int*)d_in[7];
    float* out = (float*)d_out;

    // ws: q,k,v bf16 (33.7 MB each), then packed comb table (46.4 MB) => 147.6 MB
    uint16_t* q_ws = (uint16_t*)d_ws;
    uint16_t* k_ws = q_ws + 16859136;
    uint16_t* v_ws = k_ws + 16859136;
    u32a* comb = (u32a*)((char*)d_ws + 101154816);

    const int comb_total = 64 * 3 * NTOK * 176;
    comb_pre<<<dim3((comb_total + 255) / 256), 256, 0, stream>>>(mask, rpb, rel, comb);
    qkv_kernel<<<dim3(512 * 6), 256, 0, stream>>>(x, qkv_w, qkv_b, q_ws, k_ws, v_ws);
    attn_kernel<<<dim3(512 * 3), 256, 0, stream>>>(q_ws, k_ws, v_ws, comb, out);
    proj_kernel<<<dim3(2744), 256, 0, stream>>>(proj_w, proj_b, out);
}

// Round 6
// 589.780 us; speedup vs baseline: 3.0577x; 1.3283x over previous
//
#include <hip/hip_runtime.h>
#include <stdint.h>

#define NTOK 343
#define SCALE 0.17677669529663687f

typedef uint32_t u32a __attribute__((may_alias));
typedef __attribute__((ext_vector_type(8))) short short8;
typedef short8 bfrag __attribute__((may_alias));
typedef __attribute__((ext_vector_type(4))) float f32x4;

static __device__ __forceinline__ uint16_t f2bf(float f) {
    uint32_t u = __float_as_uint(f);
    u += 0x7fffu + ((u >> 16) & 1u);
    return (uint16_t)(u >> 16);
}
static __device__ __forceinline__ float bflo(uint32_t p) { return __uint_as_float(p << 16); }
static __device__ __forceinline__ float bfhi(uint32_t p) { return __uint_as_float(p & 0xffff0000u); }

union abits { uint32_t u[4]; bfrag f; };

// K0: packed bf16 combined (mask+bias) table (unchanged from R5).
__global__ __launch_bounds__(256) void comb_pre(const float* __restrict__ mask,
                                                const float* __restrict__ rpb,
                                                const int* __restrict__ rel,
                                                u32a* __restrict__ comb) {
    int e = blockIdx.x * 256 + threadIdx.x;
    const int total = 64 * 3 * NTOK * 176;
    if (e >= total) return;
    int m16 = e & 15;
    int tp = (e >> 4) % 11;
    int rest = e / 176;
    int i = rest % NTOK;
    int wh = rest / NTOK;
    int h = wh % 3, w = wh / 3;
    int j0 = tp * 32 + m16;
    int j1 = j0 + 16;
    const float* mrow = mask + ((size_t)w * NTOK + i) * NTOK;
    const int* rrow = rel + i * NTOK;
    float c0 = mrow[j0] + rpb[rrow[j0] * 3 + h];
    float c1 = (j1 < NTOK) ? (mrow[j1] + rpb[rrow[j1] * 3 + h]) : 0.f;
    comb[e] = (uint32_t)f2bf(c0) | ((uint32_t)f2bf(c1) << 16);
}

// K1: qkv projection via MFMA. Block = 256 rows (4 waves x 4 row-tiles).
// W staged bf16 in LDS [288][104]; x -> bf16 A-frags in-register.
// SCALE baked into q-weights and q-bias.
__global__ __launch_bounds__(256) void qkv_kernel(
    const float* __restrict__ x, const float* __restrict__ qkv_w,
    const float* __restrict__ qkv_b,
    uint16_t* __restrict__ q_ws, uint16_t* __restrict__ k_ws, uint16_t* __restrict__ v_ws)
{
    __shared__ uint16_t w_l[288 * 104];
    const int tid = threadIdx.x;
    for (int e = tid; e < 288 * 96; e += 256) {
        int c = e / 96, k = e - c * 96;
        float wv = qkv_w[e];
        if (c < 96) wv *= SCALE;
        w_l[c * 104 + k] = f2bf(wv);
    }
    __syncthreads();

    const int lane = tid & 63, wv4 = tid >> 6;
    const int m = lane & 15, quad = lane >> 4;

    // per-lane bias preload (col = ct*16+m), scale baked for q cols
    float bs[18];
    #pragma unroll
    for (int ct = 0; ct < 18; ++ct) {
        int c = ct * 16 + m;
        float bb = qkv_b[c];
        bs[ct] = (c < 96) ? bb * SCALE : bb;
    }

    uint16_t* const dsts[3] = {q_ws, k_ws, v_ws};
    const int rowbase_blk = blockIdx.x * 256;

    for (int it = 0; it < 4; ++it) {
        const int rowbase = rowbase_blk + (wv4 * 4 + it) * 16;
        // x rows -> bf16 A-frags (3 K-chunks of 32)
        abits A[3];
        const float* xr = x + (size_t)(rowbase + m) * 96;
        #pragma unroll
        for (int ch = 0; ch < 3; ++ch) {
            #pragma unroll
            for (int p = 0; p < 4; ++p) {
                float x0 = xr[ch * 32 + quad * 8 + 2 * p];
                float x1 = xr[ch * 32 + quad * 8 + 2 * p + 1];
                A[ch].u[p] = (uint32_t)f2bf(x0) | ((uint32_t)f2bf(x1) << 16);
            }
        }

        f32x4 C[18];
        #pragma unroll
        for (int ct = 0; ct < 18; ++ct) C[ct] = (f32x4){0.f, 0.f, 0.f, 0.f};

        #pragma unroll
        for (int ch = 0; ch < 3; ++ch) {
            #pragma unroll
            for (int ct = 0; ct < 18; ++ct) {
                bfrag bf_ = *(const bfrag*)(w_l + (ct * 16 + m) * 104 + ch * 32 + quad * 8);
                C[ct] = __builtin_amdgcn_mfma_f32_16x16x32_bf16(A[ch].f, bf_, C[ct], 0, 0, 0);
            }
        }

        // epilogue: C rows = 4*quad+r, cols = ct*16+m; store bf16 to ws
        int bb4[4], nn4[4];
        #pragma unroll
        for (int r = 0; r < 4; ++r) {
            int rr = rowbase + 4 * quad + r;
            bb4[r] = rr / 343;
            nn4[r] = rr - bb4[r] * 343;
        }
        #pragma unroll
        for (int ct = 0; ct < 18; ++ct) {
            const int sel = ct / 6;
            const int cc = (ct % 6) * 16 + m;     // col within 96
            const int hd = cc >> 5, dd = cc & 31;
            uint16_t* dst = dsts[sel];
            #pragma unroll
            for (int r = 0; r < 4; ++r) {
                float v = C[ct][r] + bs[ct];
                dst[((size_t)(bb4[r] * 3 + hd) * NTOK + nn4[r]) * 32 + dd] = f2bf(v);
            }
        }
    }
}

// K2: MFMA attention (R5 structure). Changes: block swizzle for comb L2/L3
// locality; output written bf16 into q_ws slot (consumed q rows) for proj.
__global__ __launch_bounds__(256, 3) void attn_kernel(
    uint16_t* __restrict__ q_ws, const uint16_t* __restrict__ k_ws,
    const uint16_t* __restrict__ v_ws, const u32a* __restrict__ comb)
{
    __shared__ uint16_t vT[32 * 360];        // [d][token], stride 360
    __shared__ uint16_t pstage[4][16 * 200]; // per-wave P, stride 200

    // swizzle: 24 consecutive blocks share one window w (comb reuse)
    const int idx = blockIdx.x;
    const int w = idx / 24;
    const int rem = idx - w * 24;
    const int h = rem >> 3, bi = rem & 7;
    const int b = bi * 64 + w;
    const int bh = b * 3 + h;
    const int wh = w * 3 + h;

    const int tid = threadIdx.x, lane = tid & 63, wv = tid >> 6;
    const int m = lane & 15, quad = lane >> 4;

    const u32a* vsrc = (const u32a*)(v_ws + (size_t)bh * NTOK * 32);
    for (int e = tid; e < NTOK * 16; e += 256) {
        int tok = e >> 4, dp = e & 15;
        uint32_t vv = vsrc[e];
        vT[(2 * dp) * 360 + tok]     = (uint16_t)(vv & 0xffffu);
        vT[(2 * dp + 1) * 360 + tok] = (uint16_t)(vv >> 16);
    }
    for (int e = tid; e < 32 * 9; e += 256) {
        int d = e / 9, tok = 343 + (e % 9);
        vT[d * 360 + tok] = 0;
    }
    __syncthreads();

    uint16_t* qbase = q_ws + (size_t)bh * NTOK * 32;
    const uint16_t* kbase = k_ws + (size_t)bh * NTOK * 32;
    uint16_t* stg = pstage[wv];

    for (int ti = wv; ti < 22; ti += 4) {
        const int i0 = ti * 16;
        bfrag qf = *(const bfrag*)(qbase + (size_t)(i0 + m) * 32 + quad * 8);

        f32x4 S[22];
        #pragma unroll
        for (int t = 0; t < 22; ++t) S[t] = (f32x4){0.f, 0.f, 0.f, 0.f};

        #pragma unroll
        for (int t = 0; t < 22; ++t) {
            bfrag kf = *(const bfrag*)(kbase + (size_t)(t * 16 + m) * 32 + quad * 8);
            S[t] = __builtin_amdgcn_mfma_f32_16x16x32_bf16(qf, kf, S[t], 0, 0, 0);
        }

        float mx[4];
        #pragma unroll
        for (int r = 0; r < 4; ++r) mx[r] = -1e30f;
        #pragma unroll
        for (int r = 0; r < 4; ++r) {
            const int ir = i0 + 4 * quad + r;
            const bool rowok = (ir < NTOK);
            const u32a* crow = comb + ((size_t)(wh * NTOK + ir)) * 176 + m;
            #pragma unroll
            for (int tp = 0; tp < 11; ++tp) {
                uint32_t cw = rowok ? crow[tp * 16] : 0u;
                float sv0 = S[2 * tp][r] + bflo(cw);
                float sv1 = S[2 * tp + 1][r] + bfhi(cw);
                bool ok1 = rowok && (tp * 32 + 16 + m < NTOK);
                sv0 = rowok ? sv0 : -1e30f;
                sv1 = ok1 ? sv1 : -1e30f;
                S[2 * tp][r] = sv0;
                S[2 * tp + 1][r] = sv1;
                mx[r] = fmaxf(mx[r], fmaxf(sv0, sv1));
            }
        }

        float inv_[4], sum[4];
        #pragma unroll
        for (int r = 0; r < 4; ++r) {
            float v = mx[r];
            v = fmaxf(v, __shfl_xor(v, 1));
            v = fmaxf(v, __shfl_xor(v, 2));
            v = fmaxf(v, __shfl_xor(v, 4));
            v = fmaxf(v, __shfl_xor(v, 8));
            mx[r] = v;
            sum[r] = 0.f;
        }
        #pragma unroll
        for (int t = 0; t < 22; ++t) {
            #pragma unroll
            for (int r = 0; r < 4; ++r) {
                float e = __expf(S[t][r] - mx[r]);
                S[t][r] = e;
                sum[r] += e;
            }
        }
        #pragma unroll
        for (int r = 0; r < 4; ++r) {
            float v = sum[r];
            v += __shfl_xor(v, 1);
            v += __shfl_xor(v, 2);
            v += __shfl_xor(v, 4);
            v += __shfl_xor(v, 8);
            inv_[r] = 1.f / v;
        }

        f32x4 O0 = (f32x4){0.f, 0.f, 0.f, 0.f};
        f32x4 O1 = (f32x4){0.f, 0.f, 0.f, 0.f};
        #pragma unroll
        for (int hf = 0; hf < 2; ++hf) {
            const int tbase = hf ? 12 : 0;
            const int nt = hf ? 10 : 12;
            const int nch = hf ? 5 : 6;
            #pragma unroll
            for (int tt = 0; tt < 12; ++tt) {
                if (tt < nt) {
                    const int t = tbase + tt;
                    #pragma unroll
                    for (int r = 0; r < 4; ++r) {
                        uint32_t u = __float_as_uint(S[t][r]) + 0x8000u;
                        stg[(4 * quad + r) * 200 + tt * 16 + m] = (uint16_t)(u >> 16);
                    }
                }
            }
            __asm__ __volatile__("" ::: "memory");
            __builtin_amdgcn_s_waitcnt(0xC07F);   // lgkmcnt(0)
            __asm__ __volatile__("" ::: "memory");

            #pragma unroll
            for (int c = 0; c < 6; ++c) {
                if (c < nch) {
                    const int jj = hf * 192 + c * 32;
                    bfrag pf = *(const bfrag*)(stg + m * 200 + c * 32 + quad * 8);
                    bfrag v0 = *(const bfrag*)(vT + (size_t)m * 360 + jj + quad * 8);
                    bfrag v1 = *(const bfrag*)(vT + (size_t)(m + 16) * 360 + jj + quad * 8);
                    O0 = __builtin_amdgcn_mfma_f32_16x16x32_bf16(pf, v0, O0, 0, 0, 0);
                    O1 = __builtin_amdgcn_mfma_f32_16x16x32_bf16(pf, v1, O1, 0, 0, 0);
                }
            }
            __asm__ __volatile__("" ::: "memory");
        }

        // epilogue: bf16 attn-out into the q_ws slot this wave's tile owns
        #pragma unroll
        for (int r = 0; r < 4; ++r) {
            const int ir = i0 + 4 * quad + r;
            if (ir < NTOK) {
                uint16_t* orow = qbase + (size_t)ir * 32;
                orow[m]      = f2bf(O0[r] * inv_[r]);
                orow[m + 16] = f2bf(O1[r] * inv_[r]);
            }
        }
    }
}

// K3: output projection via MFMA. A = attn-out bf16 in q_ws (head == K-chunk,
// 16B-coalesced frags); B = proj_w bf16 in LDS; fp32 out + bias.
__global__ __launch_bounds__(256) void proj_kernel(
    const uint16_t* __restrict__ ao, const float* __restrict__ proj_w,
    const float* __restrict__ proj_b, float* __restrict__ out)
{
    __shared__ uint16_t w_l[96 * 104];
    const int tid = threadIdx.x;
    for (int e = tid; e < 96 * 96; e += 256) {
        int c = e / 96, k = e - c * 96;
        w_l[c * 104 + k] = f2bf(proj_w[e]);
    }
    __syncthreads();

    const int lane = tid & 63, wv4 = tid >> 6;
    const int m = lane & 15, quad = lane >> 4;

    float bp[6];
    #pragma unroll
    for (int ct = 0; ct < 6; ++ct) bp[ct] = proj_b[ct * 16 + m];

    const int rowbase_blk = blockIdx.x * 256;

    for (int it = 0; it < 4; ++it) {
        const int rowbase = rowbase_blk + (wv4 * 4 + it) * 16;
        const int rm = rowbase + m;
        const int bm = rm / 343;
        const int nm = rm - bm * 343;

        f32x4 C[6];
        #pragma unroll
        for (int ct = 0; ct < 6; ++ct) C[ct] = (f32x4){0.f, 0.f, 0.f, 0.f};

        #pragma unroll
        for (int ch = 0; ch < 3; ++ch) {
            bfrag af = *(const bfrag*)(ao + ((size_t)(bm * 3 + ch) * NTOK + nm) * 32 + quad * 8);
            #pragma unroll
            for (int ct = 0; ct < 6; ++ct) {
                bfrag bf_ = *(const bfrag*)(w_l + (ct * 16 + m) * 104 + ch * 32 + quad * 8);
                C[ct] = __builtin_amdgcn_mfma_f32_16x16x32_bf16(af, bf_, C[ct], 0, 0, 0);
            }
        }

        #pragma unroll
        for (int r = 0; r < 4; ++r) {
            const int rr = rowbase + 4 * quad + r;
            #pragma unroll
            for (int ct = 0; ct < 6; ++ct)
                out[(size_t)rr * 96 + ct * 16 + m] = C[ct][r] + bp[ct];
        }
    }
}

extern "C" void kernel_launch(void* const* d_in, const int* in_sizes, int n_in,
                              void* d_out, int out_size, void* d_ws, size_t ws_size,
                              hipStream_t stream) {
    const float* x      = (const float*)d_in[0];
    const float* mask   = (const float*)d_in[1];
    const float* qkv_w  = (const float*)d_in[2];
    const float* qkv_b  = (const float*)d_in[3];
    const float* proj_w = (const float*)d_in[4];
    const float* proj_b = (const float*)d_in[5];
    const float* rpb    = (const float*)d_in[6];
    const int*   rel    = (const int*)d_in[7];
    float* out = (float*)d_out;

    // ws: q,k,v bf16 (33.7 MB each), then packed comb table (46.4 MB) => 147.6 MB
    uint16_t* q_ws = (uint16_t*)d_ws;
    uint16_t* k_ws = q_ws + 16859136;
    uint16_t* v_ws = k_ws + 16859136;
    u32a* comb = (u32a*)((char*)d_ws + 101154816);

    const int comb_total = 64 * 3 * NTOK * 176;
    comb_pre<<<dim3((comb_total + 255) / 256), 256, 0, stream>>>(mask, rpb, rel, comb);
    qkv_kernel<<<dim3(686), 256, 0, stream>>>(x, qkv_w, qkv_b, q_ws, k_ws, v_ws);
    attn_kernel<<<dim3(512 * 3), 256, 0, stream>>>(q_ws, k_ws, v_ws, comb);
    proj_kernel<<<dim3(686), 256, 0, stream>>>(q_ws, proj_w, proj_b, out);
}

// Round 7
// 395.552 us; speedup vs baseline: 4.5592x; 1.4910x over previous
//
#include <hip/hip_runtime.h>
#include <stdint.h>

#define NTOK 343
#define SCALE 0.17677669529663687f

typedef uint32_t u32a __attribute__((may_alias));
typedef __attribute__((ext_vector_type(8))) short short8;
typedef short8 bfrag __attribute__((may_alias));
typedef __attribute__((ext_vector_type(4))) float f32x4;

static __device__ __forceinline__ uint16_t f2bf(float f) {
    uint32_t u = __float_as_uint(f);
    u += 0x7fffu + ((u >> 16) & 1u);
    return (uint16_t)(u >> 16);
}
static __device__ __forceinline__ float bflo(uint32_t p) { return __uint_as_float(p << 16); }
static __device__ __forceinline__ float bfhi(uint32_t p) { return __uint_as_float(p & 0xffff0000u); }

union abits { uint32_t u[4]; bfrag f; };

// K0: packed bf16 combined (mask+bias) table (unchanged).
__global__ __launch_bounds__(256) void comb_pre(const float* __restrict__ mask,
                                                const float* __restrict__ rpb,
                                                const int* __restrict__ rel,
                                                u32a* __restrict__ comb) {
    int e = blockIdx.x * 256 + threadIdx.x;
    const int total = 64 * 3 * NTOK * 176;
    if (e >= total) return;
    int m16 = e & 15;
    int tp = (e >> 4) % 11;
    int rest = e / 176;
    int i = rest % NTOK;
    int wh = rest / NTOK;
    int h = wh % 3, w = wh / 3;
    int j0 = tp * 32 + m16;
    int j1 = j0 + 16;
    const float* mrow = mask + ((size_t)w * NTOK + i) * NTOK;
    const int* rrow = rel + i * NTOK;
    float c0 = mrow[j0] + rpb[rrow[j0] * 3 + h];
    float c1 = (j1 < NTOK) ? (mrow[j1] + rpb[rrow[j1] * 3 + h]) : 0.f;
    comb[e] = (uint32_t)f2bf(c0) | ((uint32_t)f2bf(c1) << 16);
}

// K1: qkv projection via MFMA (unchanged from R6).
__global__ __launch_bounds__(256) void qkv_kernel(
    const float* __restrict__ x, const float* __restrict__ qkv_w,
    const float* __restrict__ qkv_b,
    uint16_t* __restrict__ q_ws, uint16_t* __restrict__ k_ws, uint16_t* __restrict__ v_ws)
{
    __shared__ uint16_t w_l[288 * 104];
    const int tid = threadIdx.x;
    for (int e = tid; e < 288 * 96; e += 256) {
        int c = e / 96, k = e - c * 96;
        float wv = qkv_w[e];
        if (c < 96) wv *= SCALE;
        w_l[c * 104 + k] = f2bf(wv);
    }
    __syncthreads();

    const int lane = tid & 63, wv4 = tid >> 6;
    const int m = lane & 15, quad = lane >> 4;

    float bs[18];
    #pragma unroll
    for (int ct = 0; ct < 18; ++ct) {
        int c = ct * 16 + m;
        float bb = qkv_b[c];
        bs[ct] = (c < 96) ? bb * SCALE : bb;
    }

    uint16_t* const dsts[3] = {q_ws, k_ws, v_ws};
    const int rowbase_blk = blockIdx.x * 256;

    for (int it = 0; it < 4; ++it) {
        const int rowbase = rowbase_blk + (wv4 * 4 + it) * 16;
        abits A[3];
        const float* xr = x + (size_t)(rowbase + m) * 96;
        #pragma unroll
        for (int ch = 0; ch < 3; ++ch) {
            #pragma unroll
            for (int p = 0; p < 4; ++p) {
                float x0 = xr[ch * 32 + quad * 8 + 2 * p];
                float x1 = xr[ch * 32 + quad * 8 + 2 * p + 1];
                A[ch].u[p] = (uint32_t)f2bf(x0) | ((uint32_t)f2bf(x1) << 16);
            }
        }

        f32x4 C[18];
        #pragma unroll
        for (int ct = 0; ct < 18; ++ct) C[ct] = (f32x4){0.f, 0.f, 0.f, 0.f};

        #pragma unroll
        for (int ch = 0; ch < 3; ++ch) {
            #pragma unroll
            for (int ct = 0; ct < 18; ++ct) {
                bfrag bf_ = *(const bfrag*)(w_l + (ct * 16 + m) * 104 + ch * 32 + quad * 8);
                C[ct] = __builtin_amdgcn_mfma_f32_16x16x32_bf16(A[ch].f, bf_, C[ct], 0, 0, 0);
            }
        }

        int bb4[4], nn4[4];
        #pragma unroll
        for (int r = 0; r < 4; ++r) {
            int rr = rowbase + 4 * quad + r;
            bb4[r] = rr / 343;
            nn4[r] = rr - bb4[r] * 343;
        }
        #pragma unroll
        for (int ct = 0; ct < 18; ++ct) {
            const int sel = ct / 6;
            const int cc = (ct % 6) * 16 + m;
            const int hd = cc >> 5, dd = cc & 31;
            uint16_t* dst = dsts[sel];
            #pragma unroll
            for (int r = 0; r < 4; ++r) {
                float v = C[ct][r] + bs[ct];
                dst[((size_t)(bb4[r] * 3 + hd) * NTOK + nn4[r]) * 32 + dd] = f2bf(v);
            }
        }
    }
}

// K2: MFMA attention. Block = (b,h) (swizzle reverted). K AND V staged in LDS
// (K loaded once per block -> QK reads are ds_read_b128, not 22x-redundant
// global round-trips). comb words prefetched into regs BEFORE the QK phase.
// LDS 64.5KB -> 2 blocks/CU -> 2 waves/SIMD -> 256-reg budget (bounds (256,2)).
__global__ __launch_bounds__(256, 2) void attn_kernel(
    uint16_t* __restrict__ q_ws, const uint16_t* __restrict__ k_ws,
    const uint16_t* __restrict__ v_ws, const u32a* __restrict__ comb)
{
    __shared__ uint16_t k_l[352 * 40];       // [token][32+pad], stride 40 (2-way banks)
    __shared__ uint16_t vT[32 * 360];        // [d][token], stride 360
    __shared__ uint16_t pstage[4][16 * 104]; // per-wave P quarter, stride 104

    const int bh = blockIdx.x;
    const int b = bh / 3, h = bh - b * 3, w = b & 63;
    const int tid = threadIdx.x, lane = tid & 63, wv = tid >> 6;
    const int m = lane & 15, quad = lane >> 4;
    const int wh = w * 3 + h;

    // stage K (row-major, stride 20 dwords) and V^T; zero pads
    const u32a* ksrc = (const u32a*)(k_ws + (size_t)bh * NTOK * 32);
    const u32a* vsrc = (const u32a*)(v_ws + (size_t)bh * NTOK * 32);
    u32a* k32 = (u32a*)k_l;
    for (int e = tid; e < NTOK * 16; e += 256) {
        int tok = e >> 4, dp = e & 15;
        k32[tok * 20 + dp] = ksrc[e];
        uint32_t vv = vsrc[e];
        vT[(2 * dp) * 360 + tok]     = (uint16_t)(vv & 0xffffu);
        vT[(2 * dp + 1) * 360 + tok] = (uint16_t)(vv >> 16);
    }
    for (int e = tid; e < 9 * 16; e += 256) {       // K pad rows 343..351 = 0
        int tok = 343 + (e >> 4), dp = e & 15;
        k32[tok * 20 + dp] = 0;
    }
    for (int e = tid; e < 32 * 9; e += 256) {       // vT pad cols 343..351 = 0
        int d = e / 9, tok = 343 + (e % 9);
        vT[d * 360 + tok] = 0;
    }
    __syncthreads();

    uint16_t* qbase = q_ws + (size_t)bh * NTOK * 32;
    uint16_t* stg = pstage[wv];

    for (int ti = wv; ti < 22; ti += 4) {
        const int i0 = ti * 16;
        // issue global loads FIRST: q frag + all 44 comb words (latency hides
        // under the LDS-only QK phase below)
        bfrag qf = *(const bfrag*)(qbase + (size_t)(i0 + m) * 32 + quad * 8);
        uint32_t cw[4][11];
        #pragma unroll
        for (int r = 0; r < 4; ++r) {
            const int ir = i0 + 4 * quad + r;
            const bool rowok = (ir < NTOK);
            const u32a* crow = comb + ((size_t)(wh * NTOK + ir)) * 176 + m;
            #pragma unroll
            for (int tp = 0; tp < 11; ++tp)
                cw[r][tp] = rowok ? crow[tp * 16] : 0u;   // exec-masked
        }

        // QK: K frags from LDS
        f32x4 S[22];
        #pragma unroll
        for (int t = 0; t < 22; ++t) S[t] = (f32x4){0.f, 0.f, 0.f, 0.f};
        #pragma unroll
        for (int t = 0; t < 22; ++t) {
            bfrag kf = *(const bfrag*)(k_l + (t * 16 + m) * 40 + quad * 8);
            S[t] = __builtin_amdgcn_mfma_f32_16x16x32_bf16(qf, kf, S[t], 0, 0, 0);
        }

        // apply comb + validity; track row max
        float mx[4];
        #pragma unroll
        for (int r = 0; r < 4; ++r) mx[r] = -1e30f;
        #pragma unroll
        for (int r = 0; r < 4; ++r) {
            const int ir = i0 + 4 * quad + r;
            const bool rowok = (ir < NTOK);
            #pragma unroll
            for (int tp = 0; tp < 11; ++tp) {
                float sv0 = S[2 * tp][r] + bflo(cw[r][tp]);
                float sv1 = S[2 * tp + 1][r] + bfhi(cw[r][tp]);
                bool ok1 = rowok && (tp * 32 + 16 + m < NTOK);
                sv0 = rowok ? sv0 : -1e30f;
                sv1 = ok1 ? sv1 : -1e30f;
                S[2 * tp][r] = sv0;
                S[2 * tp + 1][r] = sv1;
                mx[r] = fmaxf(mx[r], fmaxf(sv0, sv1));
            }
        }

        // softmax across the quad's 16 lanes
        float inv_[4], sum[4];
        #pragma unroll
        for (int r = 0; r < 4; ++r) {
            float v = mx[r];
            v = fmaxf(v, __shfl_xor(v, 1));
            v = fmaxf(v, __shfl_xor(v, 2));
            v = fmaxf(v, __shfl_xor(v, 4));
            v = fmaxf(v, __shfl_xor(v, 8));
            mx[r] = v;
            sum[r] = 0.f;
        }
        #pragma unroll
        for (int t = 0; t < 22; ++t) {
            #pragma unroll
            for (int r = 0; r < 4; ++r) {
                float e = __expf(S[t][r] - mx[r]);
                S[t][r] = e;
                sum[r] += e;
            }
        }
        #pragma unroll
        for (int r = 0; r < 4; ++r) {
            float v = sum[r];
            v += __shfl_xor(v, 1);
            v += __shfl_xor(v, 2);
            v += __shfl_xor(v, 4);
            v += __shfl_xor(v, 8);
            inv_[r] = 1.f / v;
        }

        // PV in 4 quarter-chunks (tiles {6,6,6,4}); all S indices constant
        f32x4 O0 = (f32x4){0.f, 0.f, 0.f, 0.f};
        f32x4 O1 = (f32x4){0.f, 0.f, 0.f, 0.f};
        #pragma unroll
        for (int qt = 0; qt < 4; ++qt) {
            const int tbase = qt * 6;
            const int nt = (qt == 3) ? 4 : 6;
            const int nch = (qt == 3) ? 2 : 3;
            #pragma unroll
            for (int tt = 0; tt < 6; ++tt) {
                if (tt < nt) {
                    const int t = tbase + tt;
                    #pragma unroll
                    for (int r = 0; r < 4; ++r) {
                        uint32_t u = __float_as_uint(S[t][r]) + 0x8000u;  // cheap RTN
                        stg[(4 * quad + r) * 104 + tt * 16 + m] = (uint16_t)(u >> 16);
                    }
                }
            }
            __asm__ __volatile__("" ::: "memory");
            __builtin_amdgcn_s_waitcnt(0xC07F);   // lgkmcnt(0); same-wave DS in-order
            __asm__ __volatile__("" ::: "memory");

            #pragma unroll
            for (int c = 0; c < 3; ++c) {
                if (c < nch) {
                    const int jj = qt * 96 + c * 32;
                    bfrag pf = *(const bfrag*)(stg + m * 104 + c * 32 + quad * 8);
                    bfrag v0 = *(const bfrag*)(vT + (size_t)m * 360 + jj + quad * 8);
                    bfrag v1 = *(const bfrag*)(vT + (size_t)(m + 16) * 360 + jj + quad * 8);
                    O0 = __builtin_amdgcn_mfma_f32_16x16x32_bf16(pf, v0, O0, 0, 0, 0);
                    O1 = __builtin_amdgcn_mfma_f32_16x16x32_bf16(pf, v1, O1, 0, 0, 0);
                }
            }
            __asm__ __volatile__("" ::: "memory");  // next quarter's writes stay after reads
        }

        // epilogue: bf16 attn-out into the consumed q_ws slot (feeds proj)
        #pragma unroll
        for (int r = 0; r < 4; ++r) {
            const int ir = i0 + 4 * quad + r;
            if (ir < NTOK) {
                uint16_t* orow = qbase + (size_t)ir * 32;
                orow[m]      = f2bf(O0[r] * inv_[r]);
                orow[m + 16] = f2bf(O1[r] * inv_[r]);
            }
        }
    }
}

// K3: output projection via MFMA (unchanged from R6).
__global__ __launch_bounds__(256) void proj_kernel(
    const uint16_t* __restrict__ ao, const float* __restrict__ proj_w,
    const float* __restrict__ proj_b, float* __restrict__ out)
{
    __shared__ uint16_t w_l[96 * 104];
    const int tid = threadIdx.x;
    for (int e = tid; e < 96 * 96; e += 256) {
        int c = e / 96, k = e - c * 96;
        w_l[c * 104 + k] = f2bf(proj_w[e]);
    }
    __syncthreads();

    const int lane = tid & 63, wv4 = tid >> 6;
    const int m = lane & 15, quad = lane >> 4;

    float bp[6];
    #pragma unroll
    for (int ct = 0; ct < 6; ++ct) bp[ct] = proj_b[ct * 16 + m];

    const int rowbase_blk = blockIdx.x * 256;

    for (int it = 0; it < 4; ++it) {
        const int rowbase = rowbase_blk + (wv4 * 4 + it) * 16;
        const int rm = rowbase + m;
        const int bm = rm / 343;
        const int nm = rm - bm * 343;

        f32x4 C[6];
        #pragma unroll
        for (int ct = 0; ct < 6; ++ct) C[ct] = (f32x4){0.f, 0.f, 0.f, 0.f};

        #pragma unroll
        for (int ch = 0; ch < 3; ++ch) {
            bfrag af = *(const bfrag*)(ao + ((size_t)(bm * 3 + ch) * NTOK + nm) * 32 + quad * 8);
            #pragma unroll
            for (int ct = 0; ct < 6; ++ct) {
                bfrag bf_ = *(const bfrag*)(w_l + (ct * 16 + m) * 104 + ch * 32 + quad * 8);
                C[ct] = __builtin_amdgcn_mfma_f32_16x16x32_bf16(af, bf_, C[ct], 0, 0, 0);
            }
        }

        #pragma unroll
        for (int r = 0; r < 4; ++r) {
            const int rr = rowbase + 4 * quad + r;
            #pragma unroll
            for (int ct = 0; ct < 6; ++ct)
                out[(size_t)rr * 96 + ct * 16 + m] = C[ct][r] + bp[ct];
        }
    }
}

extern "C" void kernel_launch(void* const* d_in, const int* in_sizes, int n_in,
                              void* d_out, int out_size, void* d_ws, size_t ws_size,
                              hipStream_t stream) {
    const float* x      = (const float*)d_in[0];
    const float* mask   = (const float*)d_in[1];
    const float* qkv_w  = (const float*)d_in[2];
    const float* qkv_b  = (const float*)d_in[3];
    const float* proj_w = (const float*)d_in[4];
    const float* proj_b = (const float*)d_in[5];
    const float* rpb    = (const float*)d_in[6];
    const int*   rel    = (const int*)d_in[7];
    float* out = (float*)d_out;

    uint16_t* q_ws = (uint16_t*)d_ws;
    uint16_t* k_ws = q_ws + 16859136;
    uint16_t* v_ws = k_ws + 16859136;
    u32a* comb = (u32a*)((char*)d_ws + 101154816);

    const int comb_total = 64 * 3 * NTOK * 176;
    comb_pre<<<dim3((comb_total + 255) / 256), 256, 0, stream>>>(mask, rpb, rel, comb);
    qkv_kernel<<<dim3(686), 256, 0, stream>>>(x, qkv_w, qkv_b, q_ws, k_ws, v_ws);
    attn_kernel<<<dim3(512 * 3), 256, 0, stream>>>(q_ws, k_ws, v_ws, comb);
    proj_kernel<<<dim3(686), 256, 0, stream>>>(q_ws, proj_w, proj_b, out);
}